// Round 4
// baseline (1239.160 us; speedup 1.0000x reference)
//
#include <hip/hip_runtime.h>
#include <math.h>

#define BB 64
#define LL 128
#define HH 1024
#define EE 512
#define VV 32000
#define MAXV 33000

typedef float f32x4 __attribute__((ext_vector_type(4)));
typedef short bf16x8 __attribute__((ext_vector_type(8)));

__device__ __forceinline__ void gload_lds16(const void* g, void* l) {
    __builtin_amdgcn_global_load_lds((const __attribute__((address_space(1))) void*)g,
                                     (__attribute__((address_space(3))) void*)l, 16, 0, 0);
}

__device__ __forceinline__ unsigned short f2bf(float f) {
    unsigned u = __float_as_uint(f);
    return (unsigned short)((u + 0x7fffu + ((u >> 16) & 1u)) >> 16);
}

// ---------------- CVT: fp32 -> bf16 (RNE), vectorized ----------------
__global__ void cvt_bf16(const float* __restrict__ in, unsigned short* __restrict__ out, int n4) {
    int i = blockIdx.x * 256 + threadIdx.x;
    if (i >= n4) return;
    float4 v = ((const float4*)in)[i];
    ushort4 o;
    o.x = f2bf(v.x); o.y = f2bf(v.y); o.z = f2bf(v.z); o.w = f2bf(v.w);
    ((ushort4*)out)[i] = o;
}

// ---------------- K0: build xa4T = [emb(tok); h], layout [(k>>2)*256 + b*4 + (k&3)] ----------------
__global__ void k0_build_x(const int* __restrict__ tok, const float* __restrict__ hidden,
                           const float* __restrict__ emb, float* __restrict__ xa4T) {
    int idx = blockIdx.x * 256 + threadIdx.x;   // 1536*64
    int b = idx / 1536, k = idx % 1536;
    float v = (k < EE) ? emb[tok[b] * EE + k] : hidden[b * HH + (k - EE)];
    xa4T[(k >> 2) * 256 + b * 4 + (k & 3)] = v;
}

// ---------------- INIT: bias-preload split-K outputs + zero accumulators ----------------
// regions: aT(8192)=attnb | gruOut(65536,4T)=combb | giT(196608)=bih | ghT(196608)=bhh | zeros(139264)
__global__ void init_ws(const float* __restrict__ attnb, const float* __restrict__ combb,
                        const float* __restrict__ bih, const float* __restrict__ bhh,
                        float* __restrict__ aT, float* __restrict__ gruOut,
                        float* __restrict__ giT, float* __restrict__ ghT,
                        float* __restrict__ zeros) {
    int idx = blockIdx.x * 256 + threadIdx.x;   // 606208 total
    if (idx < 8192) { aT[idx] = attnb[idx >> 6]; return; }
    int j = idx - 8192;
    if (j < 65536) { gruOut[j] = combb[((j >> 8) << 2) | (j & 3)]; return; }
    j -= 65536;
    if (j < 196608) { giT[j] = bih[j >> 6]; return; }
    j -= 196608;
    if (j < 196608) { ghT[j] = bhh[j >> 6]; return; }
    j -= 196608;
    zeros[j] = 0.f;
}

// ---------------- gemv body: 64 rows/block, reg-staged W tiles, x-prefetch ----------------
// out[r][b] = sum_k W[r][k] * x4T[k][b]; x in 4T layout. ACTX: relu on xA part.
// DIRECT: store acc+bias; else atomicAdd into bias-initialized out.
__device__ __forceinline__ float4 xld(const float* __restrict__ xp, int k4, int lane, bool ax) {
    float4 v = *(const float4*)&xp[k4 * 256 + lane * 4];
    if (ax) { v.x = fmaxf(v.x, 0.f); v.y = fmaxf(v.y, 0.f); v.z = fmaxf(v.z, 0.f); v.w = fmaxf(v.w, 0.f); }
    return v;
}

__device__ __forceinline__ void gemv_body(const float* __restrict__ W,
        const float* __restrict__ bias, const float* __restrict__ xA,
        const float* __restrict__ xB, int K1, int K, int kt0, int nkt_blk, int r0,
        float* __restrict__ out, int ACTX, int DIRECT, int OLAY, float* lds) {
    int tid = threadIdx.x, w = tid >> 6, lane = tid & 63;
    float acc[16];
#pragma unroll
    for (int j = 0; j < 16; ++j) acc[j] = 0.f;
    float4 st[8];
    const float* Wb = W + (size_t)r0 * K + (size_t)kt0 * 128;
#pragma unroll
    for (int i = 0; i < 8; ++i) {
        int c = i * 256 + tid;
        st[i] = *(const float4*)&Wb[(size_t)(c >> 5) * K + (c & 31) * 4];
    }
    for (int t = 0; t < nkt_blk; ++t) {
        int kt = kt0 + t;
#pragma unroll
        for (int i = 0; i < 8; ++i) {
            int c = i * 256 + tid;
            *(float4*)&lds[c * 4] = st[i];
        }
        __syncthreads();
        if (t + 1 < nkt_blk) {                  // issue next tile's loads early (T14)
            const float* Wn = W + (size_t)r0 * K + (size_t)(kt + 1) * 128;
#pragma unroll
            for (int i = 0; i < 8; ++i) {
                int c = i * 256 + tid;
                st[i] = *(const float4*)&Wn[(size_t)(c >> 5) * K + (c & 31) * 4];
            }
        }
        int kb = kt << 7;
        const float* xp = (kb < K1) ? (xA + (kb >> 2) * 256) : (xB + ((kb - K1) >> 2) * 256);
        bool ax = (kb < K1) && ACTX;
        const float* wr = &lds[(w * 16) * 128];
        float4 x0 = xld(xp, 0, lane, ax), x1 = xld(xp, 1, lane, ax);
#pragma unroll
        for (int k4 = 0; k4 < 32; ++k4) {
            float4 xc = x0;
            x0 = x1;
            if (k4 + 2 < 32) x1 = xld(xp, k4 + 2, lane, ax);
#pragma unroll
            for (int j = 0; j < 16; ++j) {
                float4 w4 = *(const float4*)&wr[j * 128 + k4 * 4];
                acc[j] += xc.x * w4.x + xc.y * w4.y + xc.z * w4.z + xc.w * w4.w;
            }
        }
        __syncthreads();
    }
#pragma unroll
    for (int j = 0; j < 16; ++j) {
        int r = r0 + w * 16 + j;
        int addr = (OLAY == 0) ? (r * 64 + lane) : ((r >> 2) * 256 + lane * 4 + (r & 3));
        if (DIRECT) out[addr] = acc[j] + bias[r];
        else atomicAdd(&out[addr], acc[j]);
    }
}

// attn: rows 128 (rb=2), K=1536, TPG=2, ng=6 -> grid 12, atomic OLAY0
__global__ __launch_bounds__(256) void gemv_attn(const float* __restrict__ W,
        const float* __restrict__ x, float* __restrict__ out) {
    __shared__ __align__(16) float lds[64 * 128];
    int rbi = blockIdx.x / 6, kg = blockIdx.x % 6;
    gemv_body(W, nullptr, x, x, 1536, 1536, kg * 2, 2, rbi * 64, out, 0, 0, 0, lds);
}

// comb: rows 1024 (rb=16), K=1536 (512 xa | 1024 ap), TPG=2, ng=6 -> grid 96, atomic OLAY1
__global__ __launch_bounds__(256) void gemv_comb(const float* __restrict__ W,
        const float* __restrict__ xA, const float* __restrict__ xB, float* __restrict__ out) {
    __shared__ __align__(16) float lds[64 * 128];
    int rbi = blockIdx.x / 6, kg = blockIdx.x % 6;
    gemv_body(W, nullptr, xA, xB, 512, 1536, kg * 2, 2, rbi * 64, out, 0, 0, 1, lds);
}

// merged GRU: blocks 0..191 Wih (rb=48, K=2048, TPG=4, ng=4, relu on xA);
//             blocks 192..383 Whh (rb=48, K=1024, TPG=2, ng=4)
__global__ __launch_bounds__(256) void gemv_gru2(const float* __restrict__ Wih,
        const float* __restrict__ Whh, const float* __restrict__ gruOut,
        const float* __restrict__ gruSel, const float* __restrict__ h4T,
        float* __restrict__ giT, float* __restrict__ ghT) {
    __shared__ __align__(16) float lds[64 * 128];
    int bi = blockIdx.x;
    if (bi < 192) {
        int rbi = bi / 4, kg = bi % 4;
        gemv_body(Wih, nullptr, gruOut, gruSel, 1024, 2048, kg * 4, 4, rbi * 64, giT, 1, 0, 0, lds);
    } else {
        bi -= 192;
        int rbi = bi / 4, kg = bi % 4;
        gemv_body(Whh, nullptr, h4T, h4T, 1024, 1024, kg * 2, 2, rbi * 64, ghT, 0, 0, 0, lds);
    }
}

// WoW: rows 32000 (rb=500), K=1024, TPG=8, ng=1 -> grid 500, DIRECT OLAY0
__global__ __launch_bounds__(256) void gemv_wow(const float* __restrict__ W,
        const float* __restrict__ bias, const float* __restrict__ x, float* __restrict__ out) {
    __shared__ __align__(16) float lds[64 * 128];
    gemv_body(W, bias, x, x, 1024, 1024, 0, 8, blockIdx.x * 64, out, 0, 1, 0, lds);
}

// ---------------- K2: softmax(a) + sel; stream enc over an L-chunk, atomic partials ----------------
__global__ __launch_bounds__(256) void k2_softmax_enc(
        const float* __restrict__ aT, const int* __restrict__ tok, const int* __restrict__ seq,
        const float* __restrict__ pprob, const float* __restrict__ enc,
        float* __restrict__ ap4T, float* __restrict__ gruSel, float* __restrict__ out3) {
    int b = blockIdx.x, lc = blockIdx.y, t = threadIdx.x;
    __shared__ float red[256];
    __shared__ float w_s[32], sel_s[32];
    float av = (t < LL) ? aT[t * 64 + b] : -1e30f;
    red[t] = av; __syncthreads();
    for (int s = 128; s > 0; s >>= 1) { if (t < s) red[t] = fmaxf(red[t], red[t + s]); __syncthreads(); }
    float m = red[0]; __syncthreads();
    float e = (t < LL) ? expf(av - m) : 0.f;
    red[t] = e; __syncthreads();
    for (int s = 128; s > 0; s >>= 1) { if (t < s) red[t] += red[t + s]; __syncthreads(); }
    float Z = red[0]; __syncthreads();
    if (t < LL) {
        float wv = e / Z;
        if (lc == 0) out3[b * LL + t] = wv;
        int l0 = lc * 32;
        if (t >= l0 && t < l0 + 32) {
            w_s[t - l0] = wv;
            sel_s[t - l0] = (seq[b * LL + t] == tok[b]) ? pprob[b * LL + t] : 0.f;
        }
    }
    __syncthreads();
    float accA[4] = {0.f,0.f,0.f,0.f}, accS[4] = {0.f,0.f,0.f,0.f};
    const float* encb = enc + (size_t)b * LL * HH + (size_t)lc * 32 * HH;
    for (int l = 0; l < 32; ++l) {
        float wl = w_s[l], sl = sel_s[l];
#pragma unroll
        for (int i = 0; i < 4; ++i) {
            float ev = encb[l * HH + t + i * 256];
            accA[i] += wl * ev;
            accS[i] += sl * truncf(ev);
        }
    }
#pragma unroll
    for (int i = 0; i < 4; ++i) {
        int h = t + i * 256;
        atomicAdd(&ap4T[(h >> 2) * 256 + b * 4 + (h & 3)], accA[i]);
        atomicAdd(&gruSel[(h >> 2) * 256 + b * 4 + (h & 3)], accS[i]);
    }
}

// ---------------- K5: GRU gates -> h_new ----------------
__global__ void k5_gates(const float* __restrict__ giT, const float* __restrict__ ghT,
                         const float* __restrict__ h4T, float* __restrict__ hn4T,
                         float* __restrict__ out2) {
    int idx = blockIdx.x * 256 + threadIdx.x;   // 65536
    int r = idx >> 6, b = idx & 63;
    float ir = giT[r * 64 + b], iz = giT[(HH + r) * 64 + b], in_ = giT[(2 * HH + r) * 64 + b];
    float hr = ghT[r * 64 + b], hz = ghT[(HH + r) * 64 + b], hn = ghT[(2 * HH + r) * 64 + b];
    float rr = 1.f / (1.f + expf(-(ir + hr)));
    float zz = 1.f / (1.f + expf(-(iz + hz)));
    float nn = tanhf(in_ + rr * hn);
    float hprev = h4T[(r >> 2) * 256 + b * 4 + (r & 3)];
    float hnew = (1.f - zz) * nn + zz * hprev;
    hn4T[(r >> 2) * 256 + b * 4 + (r & 3)] = hnew;
    out2[b * HH + r] = hnew;
}

// ---------------- K7: MFMA bf16 GEMM + fused tanh*h reduce -> sc (atomic) ----------------
__global__ __launch_bounds__(256) void k7_mfma(const unsigned short* __restrict__ encB,
        const unsigned short* __restrict__ WcB, const float* __restrict__ Wcb,
        const float* __restrict__ hn4T, float* __restrict__ sc) {
    __shared__ __align__(16) unsigned short As[128 * 64];
    __shared__ __align__(16) unsigned short Bs[128 * 64];
    __shared__ float h_s[128], bias_s[128];
    int tid = threadIdx.x, w = tid >> 6, lane = tid & 63;
    int wm = w >> 1, wn = w & 1;
    int mt = blockIdx.x >> 3, nt = blockIdx.x & 7;
    int m0 = mt * 128, n0 = nt * 128;
    if (tid < 128) {
        int n = n0 + tid;
        bias_s[tid] = Wcb[n];
        h_s[tid] = hn4T[(n >> 2) * 256 + mt * 4 + (n & 3)];
    }
    f32x4 acc[4][4];
#pragma unroll
    for (int mi = 0; mi < 4; ++mi)
#pragma unroll
        for (int ni = 0; ni < 4; ++ni) acc[mi][ni] = (f32x4){0.f, 0.f, 0.f, 0.f};

    for (int kt = 0; kt < 16; ++kt) {
        __syncthreads();
#pragma unroll
        for (int i = 0; i < 4; ++i) {
            int c = i * 256 + tid;
            int row = c >> 3, cc = c & 7;
            int lc = cc ^ (row & 7);
            gload_lds16(encB + (size_t)(m0 + row) * HH + kt * 64 + lc * 8,
                        (char*)As + (i * 256 + w * 64) * 16);
        }
#pragma unroll
        for (int i = 0; i < 4; ++i) {
            int c = i * 256 + tid;
            int row = c >> 3, cc = c & 7;
            int lc = cc ^ (row & 7);
            gload_lds16(WcB + (size_t)(n0 + row) * HH + kt * 64 + lc * 8,
                        (char*)Bs + (i * 256 + w * 64) * 16);
        }
        asm volatile("s_waitcnt vmcnt(0)");
        __syncthreads();
#pragma unroll
        for (int ks = 0; ks < 2; ++ks) {
            bf16x8 af[4], bf[4];
#pragma unroll
            for (int mi = 0; mi < 4; ++mi) {
                int rr = wm * 64 + mi * 16 + (lane & 15);
                int lk = ks * 4 + (lane >> 4);
                af[mi] = *(const bf16x8*)((const char*)As + rr * 128 + ((lk ^ (rr & 7)) * 16));
            }
#pragma unroll
            for (int ni = 0; ni < 4; ++ni) {
                int rr = wn * 64 + ni * 16 + (lane & 15);
                int lk = ks * 4 + (lane >> 4);
                bf[ni] = *(const bf16x8*)((const char*)Bs + rr * 128 + ((lk ^ (rr & 7)) * 16));
            }
#pragma unroll
            for (int mi = 0; mi < 4; ++mi)
#pragma unroll
                for (int ni = 0; ni < 4; ++ni)
                    acc[mi][ni] = __builtin_amdgcn_mfma_f32_16x16x32_bf16(af[mi], bf[ni], acc[mi][ni], 0, 0, 0);
        }
    }
    float rs[16];
#pragma unroll
    for (int z = 0; z < 16; ++z) rs[z] = 0.f;
#pragma unroll
    for (int ni = 0; ni < 4; ++ni) {
        int nl = wn * 64 + ni * 16 + (lane & 15);
        float hv = h_s[nl], bv = bias_s[nl];
#pragma unroll
        for (int mi = 0; mi < 4; ++mi)
#pragma unroll
            for (int reg = 0; reg < 4; ++reg)
                rs[mi * 4 + reg] += tanhf(acc[mi][ni][reg] + bv) * hv;
    }
#pragma unroll
    for (int z = 0; z < 16; ++z) {
        float v = rs[z];
        v += __shfl_xor(v, 1); v += __shfl_xor(v, 2);
        v += __shfl_xor(v, 4); v += __shfl_xor(v, 8);
        rs[z] = v;
    }
    if ((lane & 15) == 0) {
        int g = lane >> 4;
#pragma unroll
        for (int mi = 0; mi < 4; ++mi)
#pragma unroll
            for (int reg = 0; reg < 4; ++reg)
                atomicAdd(&sc[mt * LL + wm * 64 + mi * 16 + g * 4 + reg], rs[mi * 4 + reg]);
    }
}

// ---------------- F1: per-wave partial online max/sum over score_g (500 waves) ----------------
__global__ void f1_partial(const float* __restrict__ sgT, float* __restrict__ partM,
                           float* __restrict__ partS) {
    int gid = blockIdx.x * 256 + threadIdx.x;
    int wv = gid >> 6, lane = gid & 63;
    int v0 = wv * 64;
    float m = -1e30f, s = 0.f;
    for (int v = v0; v < v0 + 64; ++v) {
        float x = sgT[v * 64 + lane];
        float nm = fmaxf(m, x);
        s = s * expf(m - nm) + expf(x - nm);
        m = nm;
    }
    partM[wv * 64 + lane] = m;
    partS[wv * 64 + lane] = s;
}

// ---------------- F1b: combine partials + score_c -> M,Z ; write prob_c ----------------
__global__ void f1b_final(const float* __restrict__ partM, const float* __restrict__ partS,
                          const float* __restrict__ sc, float* __restrict__ Mb, float* __restrict__ Zb,
                          float* __restrict__ out4, float* __restrict__ pc) {
    int b = threadIdx.x;  // 64 threads
    float m = -1e30f, s = 0.f;
    for (int w = 0; w < 500; ++w) {
        float pm = partM[w * 64 + b], ps = partS[w * 64 + b];
        float nm = fmaxf(m, pm);
        s = s * expf(m - nm) + ps * expf(pm - nm);
        m = nm;
    }
    for (int l = 0; l < LL; ++l) {
        float x = sc[b * LL + l];
        float nm = fmaxf(m, x);
        s = s * expf(m - nm) + expf(x - nm);
        m = nm;
    }
    Mb[b] = m; Zb[b] = s;
    for (int l = 0; l < LL; ++l) {
        float p = expf(sc[b * LL + l] - m) / s;
        out4[b * LL + l] = p;
        pc[b * LL + l] = p;
    }
}

// ---------------- F2: expand prob_g into out1 ----------------
__global__ void f2_expand(const float* __restrict__ sgT, const float* __restrict__ Mb,
                          const float* __restrict__ Zb, float* __restrict__ out1) {
    int b = blockIdx.y;
    int v = blockIdx.x * 256 + threadIdx.x;
    if (v >= MAXV) return;
    float val = 0.f;
    if (v < VV) val = expf(sgT[v * 64 + b] - Mb[b]) / Zb[b];
    out1[(size_t)b * MAXV + v] = val;
}

// ---------------- F3: scatter-add prob_c ----------------
__global__ void f3_scatter(const int* __restrict__ seq, const float* __restrict__ pc,
                           float* __restrict__ out1) {
    int idx = blockIdx.x * 256 + threadIdx.x;  // 8192
    int b = idx >> 7, l = idx & 127;
    atomicAdd(&out1[(size_t)b * MAXV + seq[b * LL + l]], pc[b * LL + l]);
}

// ---------------- F4: finalize + log ----------------
__global__ void f4_log(float* __restrict__ out1) {
    int b = blockIdx.y;
    int v = blockIdx.x * 256 + threadIdx.x;
    if (v >= MAXV) return;
    float val = out1[(size_t)b * MAXV + v];
    if (v == 2 || val == 0.f) val = 1e-9f;
    out1[(size_t)b * MAXV + v] = logf(val);
}

extern "C" void kernel_launch(void* const* d_in, const int* in_sizes, int n_in,
                              void* d_out, int out_size, void* d_ws, size_t ws_size,
                              hipStream_t stream) {
    (void)in_sizes; (void)n_in; (void)out_size; (void)ws_size;
    const int*   tok    = (const int*)  d_in[0];
    const float* hidden = (const float*)d_in[1];
    const float* enc    = (const float*)d_in[2];
    const int*   seq    = (const int*)  d_in[3];
    const float* pprob  = (const float*)d_in[4];
    const float* emb    = (const float*)d_in[5];
    const float* attnW  = (const float*)d_in[6];
    const float* attnb  = (const float*)d_in[7];
    const float* combW  = (const float*)d_in[8];
    const float* combb  = (const float*)d_in[9];
    const float* Wih    = (const float*)d_in[10];
    const float* Whh    = (const float*)d_in[11];
    const float* bih    = (const float*)d_in[12];
    const float* bhh    = (const float*)d_in[13];
    const float* WoW    = (const float*)d_in[14];
    const float* Wob    = (const float*)d_in[15];
    const float* WcW    = (const float*)d_in[16];
    const float* Wcb    = (const float*)d_in[17];

    float* out1 = (float*)d_out;
    float* out2 = out1 + (size_t)BB * MAXV;
    float* out3 = out2 + BB * HH;
    float* out4 = out3 + BB * LL;

    float* ws      = (float*)d_ws;
    float* xa4T    = ws;                    // 98304
    float* h4T     = xa4T + 32768;          // h slice (k>=512)
    float* aT      = ws + 98304;            // 8192
    float* ap4T    = ws + 106496;           // 65536  (zero region start)
    float* gruSel  = ws + 172032;           // 65536
    float* sc      = ws + 237568;           // 8192   (zero region len 139264)
    float* gruOut  = ws + 245760;           // 65536 (4T, raw pre-relu)
    float* giT     = ws + 311296;           // 196608
    float* ghT     = ws + 507904;           // 196608
    float* hn4T    = ws + 704512;           // 65536
    float* sgT     = ws + 770048;           // 2048000
    float* partM   = ws + 2818048;          // 32000
    float* partS   = ws + 2850048;          // 32000
    float* Mb      = ws + 2882048;          // 64
    float* Zb      = ws + 2882112;          // 64
    float* pc      = ws + 2882176;          // 8192 -> ends 2890368 floats
    unsigned short* encB = (unsigned short*)(ws + 2890368);   // 8388608 bf16
    unsigned short* WcB  = encB + 8388608;                    // 1048576 bf16

    cvt_bf16   <<<8192, 256, 0, stream>>>(enc, encB, 2097152);
    cvt_bf16   <<<1024, 256, 0, stream>>>(WcW, WcB, 262144);
    k0_build_x <<<384, 256, 0, stream>>>(tok, hidden, emb, xa4T);
    init_ws    <<<2368, 256, 0, stream>>>(attnb, combb, bih, bhh, aT, gruOut, giT, ghT, ap4T);
    gemv_attn  <<<12, 256, 0, stream>>>(attnW, xa4T, aT);
    k2_softmax_enc<<<dim3(64, 4), 256, 0, stream>>>(aT, tok, seq, pprob, enc, ap4T, gruSel, out3);
    gemv_comb  <<<96, 256, 0, stream>>>(combW, xa4T, ap4T, gruOut);
    gemv_gru2  <<<384, 256, 0, stream>>>(Wih, Whh, gruOut, gruSel, h4T, giT, ghT);
    k5_gates   <<<256, 256, 0, stream>>>(giT, ghT, h4T, hn4T, out2);
    gemv_wow   <<<500, 256, 0, stream>>>(WoW, Wob, hn4T, sgT);
    k7_mfma    <<<512, 256, 0, stream>>>(encB, WcB, Wcb, hn4T, sc);
    f1_partial <<<125, 256, 0, stream>>>(sgT, partM, partS);
    f1b_final  <<<1, 64, 0, stream>>>(partM, partS, sc, Mb, Zb, out4, pc);
    f2_expand  <<<dim3(129, 64), 256, 0, stream>>>(sgT, Mb, Zb, out1);
    f3_scatter <<<32, 256, 0, stream>>>(seq, pc, out1);
    f4_log     <<<dim3(129, 64), 256, 0, stream>>>(out1);
}

// Round 5
// 293.212 us; speedup vs baseline: 4.2262x; 4.2262x over previous
//
#include <hip/hip_runtime.h>
#include <math.h>

#define BB 64
#define LL 128
#define HH 1024
#define EE 512
#define VV 32000
#define MAXV 33000

typedef float f32x4 __attribute__((ext_vector_type(4)));
typedef short bf16x8 __attribute__((ext_vector_type(8)));
typedef unsigned u32x4 __attribute__((ext_vector_type(4)));

__device__ __forceinline__ void gload_lds16(const void* g, void* l) {
    __builtin_amdgcn_global_load_lds((const __attribute__((address_space(1))) void*)g,
                                     (__attribute__((address_space(3))) void*)l, 16, 0, 0);
}

__device__ __forceinline__ unsigned short f2bf(float f) {
    unsigned u = __float_as_uint(f);
    return (unsigned short)((u + 0x7fffu + ((u >> 16) & 1u)) >> 16);
}

__device__ __forceinline__ unsigned pkbf(float a, float b) {
    unsigned r;
    asm("v_cvt_pk_bf16_f32 %0, %1, %2" : "=v"(r) : "v"(a), "v"(b));
    return r;
}

// ---------------- CVT: fp32 -> bf16 (RNE), vectorized ----------------
__global__ void cvt_bf16(const float* __restrict__ in, unsigned short* __restrict__ out, int n4) {
    int i = blockIdx.x * 256 + threadIdx.x;
    if (i >= n4) return;
    float4 v = ((const float4*)in)[i];
    ushort4 o;
    o.x = f2bf(v.x); o.y = f2bf(v.y); o.z = f2bf(v.z); o.w = f2bf(v.w);
    ((ushort4*)out)[i] = o;
}

// ---------------- K0: build xaB[b][0..1536) = [emb(tok); h] in bf16 ----------------
__global__ void k0_build_x(const int* __restrict__ tok, const float* __restrict__ hidden,
                           const float* __restrict__ emb, unsigned short* __restrict__ xaB) {
    int idx = blockIdx.x * 256 + threadIdx.x;   // 98304
    int b = idx / 1536, k = idx % 1536;
    float v = (k < EE) ? emb[tok[b] * EE + k] : hidden[b * HH + (k - EE)];
    xaB[b * 1536 + k] = f2bf(v);
}

// ---------------- INIT: bias-preload split-K outputs + zero accumulators ----------------
// aT(8192)=attnb | gruOutF(65536)=combb | giT(196608)=bih | ghT(196608)=bhh | zeros(139264)
__global__ void init_ws(const float* __restrict__ attnb, const float* __restrict__ combb,
                        const float* __restrict__ bih, const float* __restrict__ bhh,
                        float* __restrict__ aT, float* __restrict__ gruOutF,
                        float* __restrict__ giT, float* __restrict__ ghT,
                        float* __restrict__ zeros) {
    int idx = blockIdx.x * 256 + threadIdx.x;   // 606208 total
    if (idx < 8192) { aT[idx] = attnb[idx >> 6]; return; }
    int j = idx - 8192;
    if (j < 65536) { gruOutF[j] = combb[j >> 6]; return; }
    j -= 65536;
    if (j < 196608) { giT[j] = bih[j >> 6]; return; }
    j -= 196608;
    if (j < 196608) { ghT[j] = bhh[j >> 6]; return; }
    j -= 196608;
    zeros[j] = 0.f;
}

// ---------------- mgemm: out[r][b] = sum_k W[r][k] * x[b][k]  (x bf16, W f32->bf16 in-reg) ----------------
// 128 rows/block (4 waves x 32), all 64 batch. K-tiles of 64. Split-K via atomics into
// bias-preinit out; DIRECT=1 stores acc+bias. No LDS, no barriers.
template <int DIRECT>
__global__ __launch_bounds__(256) void mgemm(
        const float* __restrict__ W, const float* __restrict__ bias,
        const unsigned short* __restrict__ xA, int sA,
        const unsigned short* __restrict__ xB, int sB, int K1,
        int K, int Kc, int splitk, float* __restrict__ out) {
    int tid = threadIdx.x, w = tid >> 6, lane = tid & 63;
    int rb = blockIdx.x / splitk, kseg = blockIdx.x - rb * splitk;
    int r0 = rb * 128, kb0 = kseg * Kc;
    int lr = lane & 15, lk = lane >> 4;
    int nt = Kc >> 6;
    f32x4 acc[2][4];
#pragma unroll
    for (int mi = 0; mi < 2; ++mi)
#pragma unroll
        for (int nf = 0; nf < 4; ++nf) acc[mi][nf] = (f32x4){0.f, 0.f, 0.f, 0.f};
    const float* Wr0 = W + (size_t)(r0 + w * 32 + lr) * K;
    const float* Wr1 = Wr0 + (size_t)16 * K;

    for (int t = 0; t < nt; ++t) {
        int kb = kb0 + t * 64;
        // B fragments: x[b][k], 8 consecutive k per lane (global, L1/L2-hot)
        bf16x8 bfr[2][4];
#pragma unroll
        for (int ks = 0; ks < 2; ++ks)
#pragma unroll
            for (int nf = 0; nf < 4; ++nf) {
                int bcol = nf * 16 + lr;
                int kg = kb + ks * 32 + lk * 8;
                const unsigned short* xp = (kg < K1) ? (xA + bcol * sA + kg)
                                                     : (xB + bcol * sB + (kg - K1));
                bfr[ks][nf] = *(const bf16x8*)xp;
            }
        // A fragments: W f32 -> cvt_pk -> bf16x8 in regs
        bf16x8 afr[2][2];
#pragma unroll
        for (int mi = 0; mi < 2; ++mi)
#pragma unroll
            for (int ks = 0; ks < 2; ++ks) {
                const float* wp = (mi ? Wr1 : Wr0) + kb + ks * 32 + lk * 8;
                float4 w0 = *(const float4*)wp;
                float4 w1 = *(const float4*)(wp + 4);
                union { u32x4 u; bf16x8 h; } cv;
                cv.u[0] = pkbf(w0.x, w0.y); cv.u[1] = pkbf(w0.z, w0.w);
                cv.u[2] = pkbf(w1.x, w1.y); cv.u[3] = pkbf(w1.z, w1.w);
                afr[mi][ks] = cv.h;
            }
#pragma unroll
        for (int ks = 0; ks < 2; ++ks)
#pragma unroll
            for (int mi = 0; mi < 2; ++mi)
#pragma unroll
                for (int nf = 0; nf < 4; ++nf)
                    acc[mi][nf] = __builtin_amdgcn_mfma_f32_16x16x32_bf16(
                        afr[mi][ks], bfr[ks][nf], acc[mi][nf], 0, 0, 0);
    }
#pragma unroll
    for (int mi = 0; mi < 2; ++mi)
#pragma unroll
        for (int nf = 0; nf < 4; ++nf)
#pragma unroll
            for (int reg = 0; reg < 4; ++reg) {
                int r = r0 + w * 32 + mi * 16 + lk * 4 + reg;
                int bcol = nf * 16 + lr;
                float v = acc[mi][nf][reg];
                if (DIRECT) out[r * 64 + bcol] = v + bias[r];
                else atomicAdd(&out[r * 64 + bcol], v);
            }
}

// ---------------- K2: softmax(a) + sel; stream enc over an L-chunk, atomic partials ----------------
__global__ __launch_bounds__(256) void k2_softmax_enc(
        const float* __restrict__ aT, const int* __restrict__ tok, const int* __restrict__ seq,
        const float* __restrict__ pprob, const float* __restrict__ enc,
        float* __restrict__ ap4T, float* __restrict__ gruSelF, float* __restrict__ out3) {
    int b = blockIdx.x, lc = blockIdx.y, t = threadIdx.x;
    __shared__ float red[256];
    __shared__ float w_s[32], sel_s[32];
    float av = (t < LL) ? aT[t * 64 + b] : -1e30f;
    red[t] = av; __syncthreads();
    for (int s = 128; s > 0; s >>= 1) { if (t < s) red[t] = fmaxf(red[t], red[t + s]); __syncthreads(); }
    float m = red[0]; __syncthreads();
    float e = (t < LL) ? expf(av - m) : 0.f;
    red[t] = e; __syncthreads();
    for (int s = 128; s > 0; s >>= 1) { if (t < s) red[t] += red[t + s]; __syncthreads(); }
    float Z = red[0]; __syncthreads();
    if (t < LL) {
        float wv = e / Z;
        if (lc == 0) out3[b * LL + t] = wv;
        int l0 = lc * 32;
        if (t >= l0 && t < l0 + 32) {
            w_s[t - l0] = wv;
            sel_s[t - l0] = (seq[b * LL + t] == tok[b]) ? pprob[b * LL + t] : 0.f;
        }
    }
    __syncthreads();
    float accA[4] = {0.f,0.f,0.f,0.f}, accS[4] = {0.f,0.f,0.f,0.f};
    const float* encb = enc + (size_t)b * LL * HH + (size_t)lc * 32 * HH;
    for (int l = 0; l < 32; ++l) {
        float wl = w_s[l], sl = sel_s[l];
#pragma unroll
        for (int i = 0; i < 4; ++i) {
            float ev = encb[l * HH + t + i * 256];
            accA[i] += wl * ev;
            accS[i] += sl * truncf(ev);
        }
    }
#pragma unroll
    for (int i = 0; i < 4; ++i) {
        int h = t + i * 256;
        atomicAdd(&ap4T[(h >> 2) * 256 + b * 4 + (h & 3)], accA[i]);
        atomicAdd(&gruSelF[(h >> 2) * 256 + b * 4 + (h & 3)], accS[i]);
    }
}

// ---------------- cvt_ap: ap4T (f32 4T) -> apB[b][k] bf16 ----------------
__global__ void cvt_ap(const float* __restrict__ ap4T, unsigned short* __restrict__ apB) {
    int tid = blockIdx.x * 256 + threadIdx.x;  // 16384
    int b = tid & 63, kq = tid >> 6;           // kq 0..255
    float4 v = *(const float4*)&ap4T[kq * 256 + b * 4];
    ushort4 o;
    o.x = f2bf(v.x); o.y = f2bf(v.y); o.z = f2bf(v.z); o.w = f2bf(v.w);
    *(ushort4*)&apB[b * 1024 + kq * 4] = o;
}

// ---------------- cvt_gruIn: [relu(gruOutF); gruSelF] -> gruInB[b][0..2048) bf16 ----------------
__global__ void cvt_gruIn(const float* __restrict__ gruOutF, const float* __restrict__ gruSelF,
                          unsigned short* __restrict__ gruInB) {
    int tid = blockIdx.x * 256 + threadIdx.x;  // 32768
    int b = tid & 63, kq = tid >> 6;           // kq 0..511
    float4 v;
    if (kq < 256) {
        int k = kq * 4;
        v.x = fmaxf(gruOutF[(k + 0) * 64 + b], 0.f);
        v.y = fmaxf(gruOutF[(k + 1) * 64 + b], 0.f);
        v.z = fmaxf(gruOutF[(k + 2) * 64 + b], 0.f);
        v.w = fmaxf(gruOutF[(k + 3) * 64 + b], 0.f);
    } else {
        v = *(const float4*)&gruSelF[(kq - 256) * 256 + b * 4];
    }
    ushort4 o;
    o.x = f2bf(v.x); o.y = f2bf(v.y); o.z = f2bf(v.z); o.w = f2bf(v.w);
    *(ushort4*)&gruInB[b * 2048 + kq * 4] = o;
}

// ---------------- K5: GRU gates -> h_new (f32 4T + bf16 + out2) ----------------
__global__ void k5_gates(const float* __restrict__ giT, const float* __restrict__ ghT,
                         const float* __restrict__ hidden, float* __restrict__ hn4T,
                         unsigned short* __restrict__ hnB, float* __restrict__ out2) {
    int idx = blockIdx.x * 256 + threadIdx.x;   // 65536
    int r = idx >> 6, b = idx & 63;
    float ir = giT[r * 64 + b], iz = giT[(HH + r) * 64 + b], in_ = giT[(2 * HH + r) * 64 + b];
    float hr = ghT[r * 64 + b], hz = ghT[(HH + r) * 64 + b], hn = ghT[(2 * HH + r) * 64 + b];
    float rr = 1.f / (1.f + expf(-(ir + hr)));
    float zz = 1.f / (1.f + expf(-(iz + hz)));
    float nn = tanhf(in_ + rr * hn);
    float hprev = hidden[b * HH + r];
    float hnew = (1.f - zz) * nn + zz * hprev;
    hn4T[(r >> 2) * 256 + b * 4 + (r & 3)] = hnew;
    hnB[b * 1024 + r] = f2bf(hnew);
    out2[b * HH + r] = hnew;
}

// ---------------- K7: MFMA bf16 GEMM + fused tanh*h reduce -> sc (atomic) ----------------
__global__ __launch_bounds__(256) void k7_mfma(const unsigned short* __restrict__ encB,
        const unsigned short* __restrict__ WcB, const float* __restrict__ Wcb,
        const float* __restrict__ hn4T, float* __restrict__ sc) {
    __shared__ __align__(16) unsigned short As[128 * 64];
    __shared__ __align__(16) unsigned short Bs[128 * 64];
    __shared__ float h_s[128], bias_s[128];
    int tid = threadIdx.x, w = tid >> 6, lane = tid & 63;
    int wm = w >> 1, wn = w & 1;
    int mt = blockIdx.x >> 3, nt = blockIdx.x & 7;
    int m0 = mt * 128, n0 = nt * 128;
    if (tid < 128) {
        int n = n0 + tid;
        bias_s[tid] = Wcb[n];
        h_s[tid] = hn4T[(n >> 2) * 256 + mt * 4 + (n & 3)];
    }
    f32x4 acc[4][4];
#pragma unroll
    for (int mi = 0; mi < 4; ++mi)
#pragma unroll
        for (int ni = 0; ni < 4; ++ni) acc[mi][ni] = (f32x4){0.f, 0.f, 0.f, 0.f};

    for (int kt = 0; kt < 16; ++kt) {
        __syncthreads();
#pragma unroll
        for (int i = 0; i < 4; ++i) {
            int c = i * 256 + tid;
            int row = c >> 3, cc = c & 7;
            int lc = cc ^ (row & 7);
            gload_lds16(encB + (size_t)(m0 + row) * HH + kt * 64 + lc * 8,
                        (char*)As + (i * 256 + w * 64) * 16);
        }
#pragma unroll
        for (int i = 0; i < 4; ++i) {
            int c = i * 256 + tid;
            int row = c >> 3, cc = c & 7;
            int lc = cc ^ (row & 7);
            gload_lds16(WcB + (size_t)(n0 + row) * HH + kt * 64 + lc * 8,
                        (char*)Bs + (i * 256 + w * 64) * 16);
        }
        asm volatile("s_waitcnt vmcnt(0)");
        __syncthreads();
#pragma unroll
        for (int ks = 0; ks < 2; ++ks) {
            bf16x8 af[4], bf[4];
#pragma unroll
            for (int mi = 0; mi < 4; ++mi) {
                int rr = wm * 64 + mi * 16 + (lane & 15);
                int lk = ks * 4 + (lane >> 4);
                af[mi] = *(const bf16x8*)((const char*)As + rr * 128 + ((lk ^ (rr & 7)) * 16));
            }
#pragma unroll
            for (int ni = 0; ni < 4; ++ni) {
                int rr = wn * 64 + ni * 16 + (lane & 15);
                int lk = ks * 4 + (lane >> 4);
                bf[ni] = *(const bf16x8*)((const char*)Bs + rr * 128 + ((lk ^ (rr & 7)) * 16));
            }
#pragma unroll
            for (int mi = 0; mi < 4; ++mi)
#pragma unroll
                for (int ni = 0; ni < 4; ++ni)
                    acc[mi][ni] = __builtin_amdgcn_mfma_f32_16x16x32_bf16(af[mi], bf[ni], acc[mi][ni], 0, 0, 0);
        }
    }
    float rs[16];
#pragma unroll
    for (int z = 0; z < 16; ++z) rs[z] = 0.f;
#pragma unroll
    for (int ni = 0; ni < 4; ++ni) {
        int nl = wn * 64 + ni * 16 + (lane & 15);
        float hv = h_s[nl], bv = bias_s[nl];
#pragma unroll
        for (int mi = 0; mi < 4; ++mi)
#pragma unroll
            for (int reg = 0; reg < 4; ++reg)
                rs[mi * 4 + reg] += tanhf(acc[mi][ni][reg] + bv) * hv;
    }
#pragma unroll
    for (int z = 0; z < 16; ++z) {
        float v = rs[z];
        v += __shfl_xor(v, 1); v += __shfl_xor(v, 2);
        v += __shfl_xor(v, 4); v += __shfl_xor(v, 8);
        rs[z] = v;
    }
    if ((lane & 15) == 0) {
        int g = lane >> 4;
#pragma unroll
        for (int mi = 0; mi < 4; ++mi)
#pragma unroll
            for (int reg = 0; reg < 4; ++reg)
                atomicAdd(&sc[mt * LL + wm * 64 + mi * 16 + g * 4 + reg], rs[mi * 4 + reg]);
    }
}

// ---------------- F1: per-wave partial online max/sum over score_g (500 waves) ----------------
__global__ void f1_partial(const float* __restrict__ sgT, float* __restrict__ partM,
                           float* __restrict__ partS) {
    int gid = blockIdx.x * 256 + threadIdx.x;
    int wv = gid >> 6, lane = gid & 63;
    int v0 = wv * 64;
    float m = -1e30f, s = 0.f;
    for (int v = v0; v < v0 + 64; ++v) {
        float x = sgT[v * 64 + lane];
        float nm = fmaxf(m, x);
        s = s * expf(m - nm) + expf(x - nm);
        m = nm;
    }
    partM[wv * 64 + lane] = m;
    partS[wv * 64 + lane] = s;
}

// ---------------- F1b: combine partials + score_c -> M,Z ; write prob_c ----------------
__global__ void f1b_final(const float* __restrict__ partM, const float* __restrict__ partS,
                          const float* __restrict__ sc, float* __restrict__ Mb, float* __restrict__ Zb,
                          float* __restrict__ out4, float* __restrict__ pc) {
    int b = threadIdx.x;  // 64 threads
    float m = -1e30f, s = 0.f;
    for (int w = 0; w < 500; ++w) {
        float pm = partM[w * 64 + b], ps = partS[w * 64 + b];
        float nm = fmaxf(m, pm);
        s = s * expf(m - nm) + ps * expf(pm - nm);
        m = nm;
    }
    for (int l = 0; l < LL; ++l) {
        float x = sc[b * LL + l];
        float nm = fmaxf(m, x);
        s = s * expf(m - nm) + expf(x - nm);
        m = nm;
    }
    Mb[b] = m; Zb[b] = s;
    for (int l = 0; l < LL; ++l) {
        float p = expf(sc[b * LL + l] - m) / s;
        out4[b * LL + l] = p;
        pc[b * LL + l] = p;
    }
}

// ---------------- F2: expand prob_g into out1 ----------------
__global__ void f2_expand(const float* __restrict__ sgT, const float* __restrict__ Mb,
                          const float* __restrict__ Zb, float* __restrict__ out1) {
    int b = blockIdx.y;
    int v = blockIdx.x * 256 + threadIdx.x;
    if (v >= MAXV) return;
    float val = 0.f;
    if (v < VV) val = expf(sgT[v * 64 + b] - Mb[b]) / Zb[b];
    out1[(size_t)b * MAXV + v] = val;
}

// ---------------- F3: scatter-add prob_c ----------------
__global__ void f3_scatter(const int* __restrict__ seq, const float* __restrict__ pc,
                           float* __restrict__ out1) {
    int idx = blockIdx.x * 256 + threadIdx.x;  // 8192
    int b = idx >> 7, l = idx & 127;
    atomicAdd(&out1[(size_t)b * MAXV + seq[b * LL + l]], pc[b * LL + l]);
}

// ---------------- F4: finalize + log ----------------
__global__ void f4_log(float* __restrict__ out1) {
    int b = blockIdx.y;
    int v = blockIdx.x * 256 + threadIdx.x;
    if (v >= MAXV) return;
    float val = out1[(size_t)b * MAXV + v];
    if (v == 2 || val == 0.f) val = 1e-9f;
    out1[(size_t)b * MAXV + v] = logf(val);
}

extern "C" void kernel_launch(void* const* d_in, const int* in_sizes, int n_in,
                              void* d_out, int out_size, void* d_ws, size_t ws_size,
                              hipStream_t stream) {
    (void)in_sizes; (void)n_in; (void)out_size; (void)ws_size;
    const int*   tok    = (const int*)  d_in[0];
    const float* hidden = (const float*)d_in[1];
    const float* enc    = (const float*)d_in[2];
    const int*   seq    = (const int*)  d_in[3];
    const float* pprob  = (const float*)d_in[4];
    const float* emb    = (const float*)d_in[5];
    const float* attnW  = (const float*)d_in[6];
    const float* attnb  = (const float*)d_in[7];
    const float* combW  = (const float*)d_in[8];
    const float* combb  = (const float*)d_in[9];
    const float* Wih    = (const float*)d_in[10];
    const float* Whh    = (const float*)d_in[11];
    const float* bih    = (const float*)d_in[12];
    const float* bhh    = (const float*)d_in[13];
    const float* WoW    = (const float*)d_in[14];
    const float* Wob    = (const float*)d_in[15];
    const float* WcW    = (const float*)d_in[16];
    const float* Wcb    = (const float*)d_in[17];

    float* out1 = (float*)d_out;
    float* out2 = out1 + (size_t)BB * MAXV;
    float* out3 = out2 + BB * HH;
    float* out4 = out3 + BB * LL;

    float* ws      = (float*)d_ws;
    float* aT      = ws;                    // 8192
    float* ap4T    = ws + 8192;             // 65536  (zero region start)
    float* gruSelF = ws + 73728;            // 65536
    float* sc      = ws + 139264;           // 8192   (zero region len 139264)
    float* gruOutF = ws + 147456;           // 65536
    float* giT     = ws + 212992;           // 196608
    float* ghT     = ws + 409600;           // 196608
    float* hn4T    = ws + 606208;           // 65536
    float* sgT     = ws + 671744;           // 2048000
    float* partM   = ws + 2719744;          // 32000
    float* partS   = ws + 2751744;          // 32000
    float* Mb      = ws + 2783744;          // 64
    float* Zb      = ws + 2783808;          // 64
    float* pc      = ws + 2783872;          // 8192 -> 2792064
    unsigned short* encB = (unsigned short*)(ws + 2792064);   // 8388608 bf16
    unsigned short* WcB  = encB + 8388608;                    // 1048576 bf16 -> f 7510656
    unsigned short* hnB  = (unsigned short*)(ws + 7510656);   // 65536 bf16 -> f 7543424
    // transient bf16 x-buffers live inside sgT (consumed before sgT is written)
    unsigned short* xaB    = (unsigned short*)sgT;            // 98304 bf16 (f 671744..720896)
    unsigned short* apB    = (unsigned short*)(ws + 720896);  // 65536 bf16 (..753664)
    unsigned short* gruInB = (unsigned short*)(ws + 753664);  // 131072 bf16 (..819200)

    cvt_bf16   <<<8192, 256, 0, stream>>>(enc, encB, 2097152);
    cvt_bf16   <<<1024, 256, 0, stream>>>(WcW, WcB, 262144);
    k0_build_x <<<384, 256, 0, stream>>>(tok, hidden, emb, xaB);
    init_ws    <<<2368, 256, 0, stream>>>(attnb, combb, bih, bhh, aT, gruOutF, giT, ghT, ap4T);
    // attn: R=128, K=1536, splitk=6 (Kc=256) -> aT (atomic, bias pre-init)
    mgemm<0>   <<<6, 256, 0, stream>>>(attnW, nullptr, xaB, 1536, xaB, 1536, 1536, 1536, 256, 6, aT);
    k2_softmax_enc<<<dim3(64, 4), 256, 0, stream>>>(aT, tok, seq, pprob, enc, ap4T, gruSelF, out3);
    cvt_ap     <<<64, 256, 0, stream>>>(ap4T, apB);
    // comb: R=1024, K=1536 (512 xa | 1024 ap), splitk=3 (Kc=512) -> gruOutF
    mgemm<0>   <<<24, 256, 0, stream>>>(combW, nullptr, xaB, 1536, apB, 1024, 512, 1536, 512, 3, gruOutF);
    cvt_gruIn  <<<128, 256, 0, stream>>>(gruOutF, gruSelF, gruInB);
    // Wih: R=3072, K=2048, splitk=4 (Kc=512) -> giT
    mgemm<0>   <<<96, 256, 0, stream>>>(Wih, nullptr, gruInB, 2048, gruInB, 2048, 2048, 2048, 512, 4, giT);
    // Whh: R=3072, K=1024 (x = h slice of xaB), splitk=4 (Kc=256) -> ghT
    mgemm<0>   <<<96, 256, 0, stream>>>(Whh, nullptr, xaB + 512, 1536, xaB + 512, 1536, 1024, 1024, 256, 4, ghT);
    k5_gates   <<<256, 256, 0, stream>>>(giT, ghT, hidden, hn4T, hnB, out2);
    // WoW: R=32000, K=1024, direct + bias -> sgT
    mgemm<1>   <<<250, 256, 0, stream>>>(WoW, Wob, hnB, 1024, hnB, 1024, 1024, 1024, 1024, 1, sgT);
    k7_mfma    <<<512, 256, 0, stream>>>(encB, WcB, Wcb, hn4T, sc);
    f1_partial <<<125, 256, 0, stream>>>(sgT, partM, partS);
    f1b_final  <<<1, 64, 0, stream>>>(partM, partS, sc, Mb, Zb, out4, pc);
    f2_expand  <<<dim3(129, 64), 256, 0, stream>>>(sgT, Mb, Zb, out1);
    f3_scatter <<<32, 256, 0, stream>>>(seq, pc, out1);
    f4_log     <<<dim3(129, 64), 256, 0, stream>>>(out1);
}

// Round 6
// 212.159 us; speedup vs baseline: 5.8407x; 1.3820x over previous
//
#include <hip/hip_runtime.h>
#include <math.h>

#define BB 64
#define LL 128
#define HH 1024
#define EE 512
#define VV 32000
#define MAXV 33000

typedef float f32x4 __attribute__((ext_vector_type(4)));
typedef short bf16x8 __attribute__((ext_vector_type(8)));
typedef unsigned u32x4 __attribute__((ext_vector_type(4)));

__device__ __forceinline__ void gload_lds16(const void* g, void* l) {
    __builtin_amdgcn_global_load_lds((const __attribute__((address_space(1))) void*)g,
                                     (__attribute__((address_space(3))) void*)l, 16, 0, 0);
}

__device__ __forceinline__ unsigned short f2bf(float f) {
    unsigned u = __float_as_uint(f);
    return (unsigned short)((u + 0x7fffu + ((u >> 16) & 1u)) >> 16);
}

__device__ __forceinline__ unsigned pkbf(float a, float b) {
    unsigned r;
    asm("v_cvt_pk_bf16_f32 %0, %1, %2" : "=v"(r) : "v"(a), "v"(b));
    return r;
}

// online-softmax merge: (m,s) <- (m,s) ⊕ (m2,s2)
__device__ __forceinline__ void smerge(float& m, float& s, float m2, float s2) {
    float nm = fmaxf(m, m2);
    s = s * expf(m - nm) + s2 * expf(m2 - nm);
    m = nm;
}

// ---------------- CVT: fp32 -> bf16 (RNE), vectorized ----------------
__global__ void cvt_bf16(const float* __restrict__ in, unsigned short* __restrict__ out, int n4) {
    int i = blockIdx.x * 256 + threadIdx.x;
    if (i >= n4) return;
    float4 v = ((const float4*)in)[i];
    ushort4 o;
    o.x = f2bf(v.x); o.y = f2bf(v.y); o.z = f2bf(v.z); o.w = f2bf(v.w);
    ((ushort4*)out)[i] = o;
}

// ---------------- K0: build xaB[b][0..1536) = [emb(tok); h] in bf16 ----------------
__global__ void k0_build_x(const int* __restrict__ tok, const float* __restrict__ hidden,
                           const float* __restrict__ emb, unsigned short* __restrict__ xaB) {
    int idx = blockIdx.x * 256 + threadIdx.x;   // 98304
    int b = idx / 1536, k = idx % 1536;
    float v = (k < EE) ? emb[tok[b] * EE + k] : hidden[b * HH + (k - EE)];
    xaB[b * 1536 + k] = f2bf(v);
}

// ---------------- INIT: bias-preload split-K outputs + zero accumulators ----------------
__global__ void init_ws(const float* __restrict__ attnb, const float* __restrict__ combb,
                        const float* __restrict__ bih, const float* __restrict__ bhh,
                        float* __restrict__ aT, float* __restrict__ gruOutF,
                        float* __restrict__ giT, float* __restrict__ ghT,
                        float* __restrict__ zeros) {
    int idx = blockIdx.x * 256 + threadIdx.x;   // 606208 total
    if (idx < 8192) { aT[idx] = attnb[idx >> 6]; return; }
    int j = idx - 8192;
    if (j < 65536) { gruOutF[j] = combb[j >> 6]; return; }
    j -= 65536;
    if (j < 196608) { giT[j] = bih[j >> 6]; return; }
    j -= 196608;
    if (j < 196608) { ghT[j] = bhh[j >> 6]; return; }
    j -= 196608;
    zeros[j] = 0.f;
}

// ---------------- mgemm: out[r][b] = sum_k W[r][k] * x[b][k]  (x bf16, W f32->bf16 in-reg) ----------------
template <int DIRECT>
__global__ __launch_bounds__(256) void mgemm(
        const float* __restrict__ W, const float* __restrict__ bias,
        const unsigned short* __restrict__ xA, int sA,
        const unsigned short* __restrict__ xB, int sB, int K1,
        int K, int Kc, int splitk, float* __restrict__ out) {
    int tid = threadIdx.x, w = tid >> 6, lane = tid & 63;
    int rb = blockIdx.x / splitk, kseg = blockIdx.x - rb * splitk;
    int r0 = rb * 128, kb0 = kseg * Kc;
    int lr = lane & 15, lk = lane >> 4;
    int nt = Kc >> 6;
    f32x4 acc[2][4];
#pragma unroll
    for (int mi = 0; mi < 2; ++mi)
#pragma unroll
        for (int nf = 0; nf < 4; ++nf) acc[mi][nf] = (f32x4){0.f, 0.f, 0.f, 0.f};
    const float* Wr0 = W + (size_t)(r0 + w * 32 + lr) * K;
    const float* Wr1 = Wr0 + (size_t)16 * K;

    for (int t = 0; t < nt; ++t) {
        int kb = kb0 + t * 64;
        bf16x8 bfr[2][4];
#pragma unroll
        for (int ks = 0; ks < 2; ++ks)
#pragma unroll
            for (int nf = 0; nf < 4; ++nf) {
                int bcol = nf * 16 + lr;
                int kg = kb + ks * 32 + lk * 8;
                const unsigned short* xp = (kg < K1) ? (xA + bcol * sA + kg)
                                                     : (xB + bcol * sB + (kg - K1));
                bfr[ks][nf] = *(const bf16x8*)xp;
            }
        bf16x8 afr[2][2];
#pragma unroll
        for (int mi = 0; mi < 2; ++mi)
#pragma unroll
            for (int ks = 0; ks < 2; ++ks) {
                const float* wp = (mi ? Wr1 : Wr0) + kb + ks * 32 + lk * 8;
                float4 w0 = *(const float4*)wp;
                float4 w1 = *(const float4*)(wp + 4);
                union { u32x4 u; bf16x8 h; } cv;
                cv.u[0] = pkbf(w0.x, w0.y); cv.u[1] = pkbf(w0.z, w0.w);
                cv.u[2] = pkbf(w1.x, w1.y); cv.u[3] = pkbf(w1.z, w1.w);
                afr[mi][ks] = cv.h;
            }
#pragma unroll
        for (int ks = 0; ks < 2; ++ks)
#pragma unroll
            for (int mi = 0; mi < 2; ++mi)
#pragma unroll
                for (int nf = 0; nf < 4; ++nf)
                    acc[mi][nf] = __builtin_amdgcn_mfma_f32_16x16x32_bf16(
                        afr[mi][ks], bfr[ks][nf], acc[mi][nf], 0, 0, 0);
    }
#pragma unroll
    for (int mi = 0; mi < 2; ++mi)
#pragma unroll
        for (int nf = 0; nf < 4; ++nf)
#pragma unroll
            for (int reg = 0; reg < 4; ++reg) {
                int r = r0 + w * 32 + mi * 16 + lk * 4 + reg;
                int bcol = nf * 16 + lr;
                float v = acc[mi][nf][reg];
                if (DIRECT) out[r * 64 + bcol] = v + bias[r];
                else atomicAdd(&out[r * 64 + bcol], v);
            }
}

// ---------------- K2: softmax(a) + sel; stream enc over an L-chunk, atomic partials ----------------
__global__ __launch_bounds__(256) void k2_softmax_enc(
        const float* __restrict__ aT, const int* __restrict__ tok, const int* __restrict__ seq,
        const float* __restrict__ pprob, const float* __restrict__ enc,
        float* __restrict__ ap4T, float* __restrict__ gruSelF, float* __restrict__ out3) {
    int b = blockIdx.x, lc = blockIdx.y, t = threadIdx.x;
    __shared__ float red[256];
    __shared__ float w_s[32], sel_s[32];
    float av = (t < LL) ? aT[t * 64 + b] : -1e30f;
    red[t] = av; __syncthreads();
    for (int s = 128; s > 0; s >>= 1) { if (t < s) red[t] = fmaxf(red[t], red[t + s]); __syncthreads(); }
    float m = red[0]; __syncthreads();
    float e = (t < LL) ? expf(av - m) : 0.f;
    red[t] = e; __syncthreads();
    for (int s = 128; s > 0; s >>= 1) { if (t < s) red[t] += red[t + s]; __syncthreads(); }
    float Z = red[0]; __syncthreads();
    if (t < LL) {
        float wv = e / Z;
        if (lc == 0) out3[b * LL + t] = wv;
        int l0 = lc * 32;
        if (t >= l0 && t < l0 + 32) {
            w_s[t - l0] = wv;
            sel_s[t - l0] = (seq[b * LL + t] == tok[b]) ? pprob[b * LL + t] : 0.f;
        }
    }
    __syncthreads();
    float accA[4] = {0.f,0.f,0.f,0.f}, accS[4] = {0.f,0.f,0.f,0.f};
    const float* encb = enc + (size_t)b * LL * HH + (size_t)lc * 32 * HH;
    for (int l = 0; l < 32; ++l) {
        float wl = w_s[l], sl = sel_s[l];
#pragma unroll
        for (int i = 0; i < 4; ++i) {
            float ev = encb[l * HH + t + i * 256];
            accA[i] += wl * ev;
            accS[i] += sl * truncf(ev);
        }
    }
#pragma unroll
    for (int i = 0; i < 4; ++i) {
        int h = t + i * 256;
        atomicAdd(&ap4T[(h >> 2) * 256 + b * 4 + (h & 3)], accA[i]);
        atomicAdd(&gruSelF[(h >> 2) * 256 + b * 4 + (h & 3)], accS[i]);
    }
}

// ---------------- cvt_ap: ap4T (f32 4T) -> apB[b][k] bf16 ----------------
__global__ void cvt_ap(const float* __restrict__ ap4T, unsigned short* __restrict__ apB) {
    int tid = blockIdx.x * 256 + threadIdx.x;  // 16384
    int b = tid & 63, kq = tid >> 6;           // kq 0..255
    float4 v = *(const float4*)&ap4T[kq * 256 + b * 4];
    ushort4 o;
    o.x = f2bf(v.x); o.y = f2bf(v.y); o.z = f2bf(v.z); o.w = f2bf(v.w);
    *(ushort4*)&apB[b * 1024 + kq * 4] = o;
}

// ---------------- cvt_gruIn: [relu(gruOutF); gruSelF] -> gruInB[b][0..2048) bf16 ----------------
__global__ void cvt_gruIn(const float* __restrict__ gruOutF, const float* __restrict__ gruSelF,
                          unsigned short* __restrict__ gruInB) {
    int tid = blockIdx.x * 256 + threadIdx.x;  // 32768
    int b = tid & 63, kq = tid >> 6;           // kq 0..511
    float4 v;
    if (kq < 256) {
        int k = kq * 4;
        v.x = fmaxf(gruOutF[(k + 0) * 64 + b], 0.f);
        v.y = fmaxf(gruOutF[(k + 1) * 64 + b], 0.f);
        v.z = fmaxf(gruOutF[(k + 2) * 64 + b], 0.f);
        v.w = fmaxf(gruOutF[(k + 3) * 64 + b], 0.f);
    } else {
        v = *(const float4*)&gruSelF[(kq - 256) * 256 + b * 4];
    }
    ushort4 o;
    o.x = f2bf(v.x); o.y = f2bf(v.y); o.z = f2bf(v.z); o.w = f2bf(v.w);
    *(ushort4*)&gruInB[b * 2048 + kq * 4] = o;
}

// ---------------- K5: GRU gates -> h_new (f32 4T + bf16 + out2) ----------------
__global__ void k5_gates(const float* __restrict__ giT, const float* __restrict__ ghT,
                         const float* __restrict__ hidden, float* __restrict__ hn4T,
                         unsigned short* __restrict__ hnB, float* __restrict__ out2) {
    int idx = blockIdx.x * 256 + threadIdx.x;   // 65536
    int r = idx >> 6, b = idx & 63;
    float ir = giT[r * 64 + b], iz = giT[(HH + r) * 64 + b], in_ = giT[(2 * HH + r) * 64 + b];
    float hr = ghT[r * 64 + b], hz = ghT[(HH + r) * 64 + b], hn = ghT[(2 * HH + r) * 64 + b];
    float rr = 1.f / (1.f + expf(-(ir + hr)));
    float zz = 1.f / (1.f + expf(-(iz + hz)));
    float nn = tanhf(in_ + rr * hn);
    float hprev = hidden[b * HH + r];
    float hnew = (1.f - zz) * nn + zz * hprev;
    hn4T[(r >> 2) * 256 + b * 4 + (r & 3)] = hnew;
    hnB[b * 1024 + r] = f2bf(hnew);
    out2[b * HH + r] = hnew;
}

// ---------------- K7: MFMA bf16 GEMM + fused tanh*h reduce -> sc (atomic) ----------------
// XCD-aware swizzle (T1): nwg=512, 8 XCDs -> each XCD gets 8 consecutive mt x all nt
// (A 2MB + B 2MB per-XCD L2-resident instead of 8x A over-fetch).
__global__ __launch_bounds__(256) void k7_mfma(const unsigned short* __restrict__ encB,
        const unsigned short* __restrict__ WcB, const float* __restrict__ Wcb,
        const float* __restrict__ hn4T, float* __restrict__ sc) {
    __shared__ __align__(16) unsigned short As[128 * 64];
    __shared__ __align__(16) unsigned short Bs[128 * 64];
    __shared__ float h_s[128], bias_s[128];
    int tid = threadIdx.x, w = tid >> 6, lane = tid & 63;
    int wm = w >> 1, wn = w & 1;
    int bid = blockIdx.x;
    int swz = (bid & 7) * 64 + (bid >> 3);   // bijective, 512 = 8*64
    int mt = swz >> 3, nt = swz & 7;
    int m0 = mt * 128, n0 = nt * 128;
    if (tid < 128) {
        int n = n0 + tid;
        bias_s[tid] = Wcb[n];
        h_s[tid] = hn4T[(n >> 2) * 256 + mt * 4 + (n & 3)];
    }
    f32x4 acc[4][4];
#pragma unroll
    for (int mi = 0; mi < 4; ++mi)
#pragma unroll
        for (int ni = 0; ni < 4; ++ni) acc[mi][ni] = (f32x4){0.f, 0.f, 0.f, 0.f};

    for (int kt = 0; kt < 16; ++kt) {
        __syncthreads();
#pragma unroll
        for (int i = 0; i < 4; ++i) {
            int c = i * 256 + tid;
            int row = c >> 3, cc = c & 7;
            int lc = cc ^ (row & 7);
            gload_lds16(encB + (size_t)(m0 + row) * HH + kt * 64 + lc * 8,
                        (char*)As + (i * 256 + w * 64) * 16);
        }
#pragma unroll
        for (int i = 0; i < 4; ++i) {
            int c = i * 256 + tid;
            int row = c >> 3, cc = c & 7;
            int lc = cc ^ (row & 7);
            gload_lds16(WcB + (size_t)(n0 + row) * HH + kt * 64 + lc * 8,
                        (char*)Bs + (i * 256 + w * 64) * 16);
        }
        asm volatile("s_waitcnt vmcnt(0)");
        __syncthreads();
#pragma unroll
        for (int ks = 0; ks < 2; ++ks) {
            bf16x8 af[4], bf[4];
#pragma unroll
            for (int mi = 0; mi < 4; ++mi) {
                int rr = wm * 64 + mi * 16 + (lane & 15);
                int lk = ks * 4 + (lane >> 4);
                af[mi] = *(const bf16x8*)((const char*)As + rr * 128 + ((lk ^ (rr & 7)) * 16));
            }
#pragma unroll
            for (int ni = 0; ni < 4; ++ni) {
                int rr = wn * 64 + ni * 16 + (lane & 15);
                int lk = ks * 4 + (lane >> 4);
                bf[ni] = *(const bf16x8*)((const char*)Bs + rr * 128 + ((lk ^ (rr & 7)) * 16));
            }
#pragma unroll
            for (int mi = 0; mi < 4; ++mi)
#pragma unroll
                for (int ni = 0; ni < 4; ++ni)
                    acc[mi][ni] = __builtin_amdgcn_mfma_f32_16x16x32_bf16(af[mi], bf[ni], acc[mi][ni], 0, 0, 0);
        }
    }
    float rs[16];
#pragma unroll
    for (int z = 0; z < 16; ++z) rs[z] = 0.f;
#pragma unroll
    for (int ni = 0; ni < 4; ++ni) {
        int nl = wn * 64 + ni * 16 + (lane & 15);
        float hv = h_s[nl], bv = bias_s[nl];
#pragma unroll
        for (int mi = 0; mi < 4; ++mi)
#pragma unroll
            for (int reg = 0; reg < 4; ++reg)
                rs[mi * 4 + reg] += tanhf(acc[mi][ni][reg] + bv) * hv;
    }
#pragma unroll
    for (int z = 0; z < 16; ++z) {
        float v = rs[z];
        v += __shfl_xor(v, 1); v += __shfl_xor(v, 2);
        v += __shfl_xor(v, 4); v += __shfl_xor(v, 8);
        rs[z] = v;
    }
    if ((lane & 15) == 0) {
        int g = lane >> 4;
#pragma unroll
        for (int mi = 0; mi < 4; ++mi)
#pragma unroll
            for (int reg = 0; reg < 4; ++reg)
                atomicAdd(&sc[mt * LL + wm * 64 + mi * 16 + g * 4 + reg], rs[mi * 4 + reg]);
    }
}

// ---------------- F1: per-wave partial online max/sum over score_g; TRANSPOSED out ----------------
__global__ void f1_partial(const float* __restrict__ sgT, float* __restrict__ partMt,
                           float* __restrict__ partSt) {
    int gid = blockIdx.x * 256 + threadIdx.x;
    int wv = gid >> 6, lane = gid & 63;   // 500 waves, lane = b
    int v0 = wv * 64;
    float m = -1e30f, s = 0.f;
    for (int v = v0; v < v0 + 64; ++v) {
        float x = sgT[v * 64 + lane];
        float nm = fmaxf(m, x);
        s = s * expf(m - nm) + expf(x - nm);
        m = nm;
    }
    partMt[lane * 512 + wv] = m;
    partSt[lane * 512 + wv] = s;
}

// ---------------- F1c: tree-combine partials + sc -> M,Z ; write prob_c (block per b) ----------------
__global__ __launch_bounds__(256) void f1c_final(const float* __restrict__ partMt,
        const float* __restrict__ partSt, const float* __restrict__ sc,
        float* __restrict__ Mb, float* __restrict__ Zb,
        float* __restrict__ out4, float* __restrict__ pc) {
    int b = blockIdx.x, t = threadIdx.x;
    __shared__ float mred[256], sred[256];
    float m = -1e30f, s = 0.f;
    for (int w = t; w < 500; w += 256)
        smerge(m, s, partMt[b * 512 + w], partSt[b * 512 + w]);
    if (t < 128) smerge(m, s, sc[b * LL + t], 1.0f);
    mred[t] = m; sred[t] = s; __syncthreads();
    for (int st = 128; st > 0; st >>= 1) {
        if (t < st) {
            float mm = mred[t], ss = sred[t];
            smerge(mm, ss, mred[t + st], sred[t + st]);
            mred[t] = mm; sred[t] = ss;
        }
        __syncthreads();
    }
    float M = mred[0], Z = sred[0];
    if (t == 0) { Mb[b] = M; Zb[b] = Z; }
    if (t < 128) {
        float p = expf(sc[b * LL + t] - M) / Z;
        out4[b * LL + t] = p;
        pc[b * LL + t] = p;
    }
}

// ---------------- F2: expand prob_g into out1 ----------------
__global__ void f2_expand(const float* __restrict__ sgT, const float* __restrict__ Mb,
                          const float* __restrict__ Zb, float* __restrict__ out1) {
    int b = blockIdx.y;
    int v = blockIdx.x * 256 + threadIdx.x;
    if (v >= MAXV) return;
    float val = 0.f;
    if (v < VV) val = expf(sgT[v * 64 + b] - Mb[b]) / Zb[b];
    out1[(size_t)b * MAXV + v] = val;
}

// ---------------- F3: scatter-add prob_c ----------------
__global__ void f3_scatter(const int* __restrict__ seq, const float* __restrict__ pc,
                           float* __restrict__ out1) {
    int idx = blockIdx.x * 256 + threadIdx.x;  // 8192
    int b = idx >> 7, l = idx & 127;
    atomicAdd(&out1[(size_t)b * MAXV + seq[b * LL + l]], pc[b * LL + l]);
}

// ---------------- F4: finalize + log ----------------
__global__ void f4_log(float* __restrict__ out1) {
    int b = blockIdx.y;
    int v = blockIdx.x * 256 + threadIdx.x;
    if (v >= MAXV) return;
    float val = out1[(size_t)b * MAXV + v];
    if (v == 2 || val == 0.f) val = 1e-9f;
    out1[(size_t)b * MAXV + v] = logf(val);
}

extern "C" void kernel_launch(void* const* d_in, const int* in_sizes, int n_in,
                              void* d_out, int out_size, void* d_ws, size_t ws_size,
                              hipStream_t stream) {
    (void)in_sizes; (void)n_in; (void)out_size; (void)ws_size;
    const int*   tok    = (const int*)  d_in[0];
    const float* hidden = (const float*)d_in[1];
    const float* enc    = (const float*)d_in[2];
    const int*   seq    = (const int*)  d_in[3];
    const float* pprob  = (const float*)d_in[4];
    const float* emb    = (const float*)d_in[5];
    const float* attnW  = (const float*)d_in[6];
    const float* attnb  = (const float*)d_in[7];
    const float* combW  = (const float*)d_in[8];
    const float* combb  = (const float*)d_in[9];
    const float* Wih    = (const float*)d_in[10];
    const float* Whh    = (const float*)d_in[11];
    const float* bih    = (const float*)d_in[12];
    const float* bhh    = (const float*)d_in[13];
    const float* WoW    = (const float*)d_in[14];
    const float* Wob    = (const float*)d_in[15];
    const float* WcW    = (const float*)d_in[16];
    const float* Wcb    = (const float*)d_in[17];

    float* out1 = (float*)d_out;
    float* out2 = out1 + (size_t)BB * MAXV;
    float* out3 = out2 + BB * HH;
    float* out4 = out3 + BB * LL;

    float* ws      = (float*)d_ws;
    float* aT      = ws;                    // 8192
    float* ap4T    = ws + 8192;             // 65536  (zero region start)
    float* gruSelF = ws + 73728;            // 65536
    float* sc      = ws + 139264;           // 8192   (zero region len 139264)
    float* gruOutF = ws + 147456;           // 65536
    float* giT     = ws + 212992;           // 196608
    float* ghT     = ws + 409600;           // 196608
    float* hn4T    = ws + 606208;           // 65536
    float* sgT     = ws + 671744;           // 2048000
    float* partMt  = ws + 2719744;          // 32768 (64 x 512)
    float* partSt  = ws + 2752512;          // 32768
    float* Mb      = ws + 2785280;          // 64
    float* Zb      = ws + 2785344;          // 64
    float* pc      = ws + 2785408;          // 8192 -> 2793600
    unsigned short* encB = (unsigned short*)(ws + 2793600);   // 8388608 bf16 -> f 6987904
    unsigned short* WcB  = encB + 8388608;                    // 1048576 bf16 -> f 7512192
    unsigned short* hnB  = (unsigned short*)(ws + 7512192);   // 65536 bf16 -> f 7544960
    // transient bf16 x-buffers live inside sgT (consumed before sgT is written)
    unsigned short* xaB    = (unsigned short*)sgT;            // 98304 bf16 (f 671744..720896)
    unsigned short* apB    = (unsigned short*)(ws + 720896);  // 65536 bf16 (..753664)
    unsigned short* gruInB = (unsigned short*)(ws + 753664);  // 131072 bf16 (..819200)

    cvt_bf16   <<<8192, 256, 0, stream>>>(enc, encB, 2097152);
    cvt_bf16   <<<1024, 256, 0, stream>>>(WcW, WcB, 262144);
    k0_build_x <<<384, 256, 0, stream>>>(tok, hidden, emb, xaB);
    init_ws    <<<2368, 256, 0, stream>>>(attnb, combb, bih, bhh, aT, gruOutF, giT, ghT, ap4T);
    mgemm<0>   <<<6, 256, 0, stream>>>(attnW, nullptr, xaB, 1536, xaB, 1536, 1536, 1536, 256, 6, aT);
    k2_softmax_enc<<<dim3(64, 4), 256, 0, stream>>>(aT, tok, seq, pprob, enc, ap4T, gruSelF, out3);
    cvt_ap     <<<64, 256, 0, stream>>>(ap4T, apB);
    mgemm<0>   <<<24, 256, 0, stream>>>(combW, nullptr, xaB, 1536, apB, 1024, 512, 1536, 512, 3, gruOutF);
    cvt_gruIn  <<<128, 256, 0, stream>>>(gruOutF, gruSelF, gruInB);
    mgemm<0>   <<<96, 256, 0, stream>>>(Wih, nullptr, gruInB, 2048, gruInB, 2048, 2048, 2048, 512, 4, giT);
    mgemm<0>   <<<96, 256, 0, stream>>>(Whh, nullptr, xaB + 512, 1536, xaB + 512, 1536, 1024, 1024, 256, 4, ghT);
    k5_gates   <<<256, 256, 0, stream>>>(giT, ghT, hidden, hn4T, hnB, out2);
    mgemm<1>   <<<250, 256, 0, stream>>>(WoW, Wob, hnB, 1024, hnB, 1024, 1024, 1024, 1024, 1, sgT);
    k7_mfma    <<<512, 256, 0, stream>>>(encB, WcB, Wcb, hn4T, sc);
    f1_partial <<<125, 256, 0, stream>>>(sgT, partMt, partSt);
    f1c_final  <<<64, 256, 0, stream>>>(partMt, partSt, sc, Mb, Zb, out4, pc);
    f2_expand  <<<dim3(129, 64), 256, 0, stream>>>(sgT, Mb, Zb, out1);
    f3_scatter <<<32, 256, 0, stream>>>(seq, pc, out1);
    f4_log     <<<dim3(129, 64), 256, 0, stream>>>(out1);
}